// Round 12
// baseline (77.891 us; speedup 1.0000x reference)
//
#include <hip/hip_runtime.h>
#include <math.h>

// Histogram2D, sparse formulation: each point adds its exact-i32 8x8 window
// outer-product qx[i]*qy[j] into a per-block LDS histogram via LDS atomics
// (CU-local). Ladder: R8 dense-MFMA 84.5 -> R17 sparse 81.9 -> R18 halve
// partials (256 blk x 1024 thr, 8MiB) 76.4 [prediction MATCHED 76-78.5].
// Decomposition: poison fill 41.2 (fixed floor, 256MiB d_ws @ 81% HBM peak)
// + harness tiny-dispatch floor ~20-22 + hist ~7-9 + reduce ~3-4.
// FAILED experiments (never revisit): R10 device atomics (+12.7, far
// coherence point), R11 software grid barrier (+150, agent-scope spin
// thrashes coherence fabric), R12 100%-occupancy dense (neutral: cost
// scaled with work, not scheduling).
// R19 (this round): kill the erf from the hot loop. Window weights are a
// pure function of delta = spos - round(spos) in [-0.5,0.5), same for both
// axes -> 1024-entry x 8B LDS LUT built once per block (1024 thr x 9 erf).
// Per point per axis: ds_read_b64 + 8x bfe unpack replaces 9 erf_fast
// (~540 -> ~180 cyc/pt VALU). LUT step 1/1024 -> weight err <= 0.08 < 0.5
// quant LSB (absmax shift < 1e-6). Clamp removed: window [round-4,round+3]
// unclamped, out-of-range bins per-lane predicated (provably identical
// in-range values to the old clamped window; far-tail mass dropped exactly
// as reference drops out-of-grid mass). bsum = sxin*syin (in-range-only
// masks) to match reference hist.sum() normalization. Skip zero-product
// atomics per-lane + all-zero rows per-wave (outer ring ~always 0).
// Predicted 76.4 -> 73.5-75.5; if neutral, hist is LDS-atomic floor and
// controllable residue ~= reduce kernel only.
// LDS: hist 64.5 KiB (stride 129 -> bank ~(bx+by+c)%32 uniform) + LUT 8 KiB
// -> 1 block/CU, 16 waves. Numerics: A&S erf, q=rint(w*320), exact i32,
// bf16 partials, same reduce kernel.

#define NBINS   128
#define NB2     (NBINS * NBINS)
#define LDH     129               // padded LDS row stride (i32)
#define THREADS 1024
#define NBLOCKS 256
#define QSCALE  320.0f

static __device__ __forceinline__ unsigned short f2bf(float f) {
    unsigned int b = __float_as_uint(f);
    b += 0x7fff + ((b >> 16) & 1);            // RNE
    return (unsigned short)(b >> 16);
}
static __device__ __forceinline__ float bf2f(unsigned short u) {
    return __uint_as_float((unsigned int)u << 16);
}

// Abramowitz-Stegun 7.1.26: |err| <= 1.5e-7, branch-free.
static __device__ __forceinline__ float erf_fast(float x) {
    const float ax = fabsf(x);
    const float t  = __builtin_amdgcn_rcpf(fmaf(0.3275911f, ax, 1.0f));
    const float e  = __expf(-x * x);          // v_exp_f32; inf^2 -> e=0 safe
    float p = fmaf(1.061405429f, t, -1.453152027f);
    p = fmaf(p, t, 1.421413741f);
    p = fmaf(p, t, -0.284496736f);
    p = fmaf(p, t, 0.254829592f);
    p = p * t;
    return copysignf(fmaf(-p, e, 1.0f), x);
}

__global__ __launch_bounds__(THREADS, 4) void hist_sparse_kernel(
    const float* __restrict__ x,
    const float* __restrict__ edges_x,
    const float* __restrict__ edges_y,
    unsigned short* __restrict__ partials,   // bf16 [block][16384]
    float* __restrict__ btot,                // f32 [256]
    int n)
{
    __shared__ int lh[NBINS * LDH];          // 64.5 KiB
    __shared__ int2 lut[1024];               // 8 KiB: 8 u8 weights per delta
    __shared__ int xw[16];

    const int tid  = threadIdx.x;
    const int lane = tid & 63;
    const int wv   = tid >> 6;               // 0..15

    // Build weight LUT: entry e covers delta = (e+0.5)/1024 - 0.5.
    // q[k] = rint(0.5*(erf((k-3-d)*cc) - erf((k-4-d)*cc)) * QSCALE), k=0..7.
    {
        const float cc = 0.7071067811865476f;
        const float d = ((float)tid + 0.5f) * (1.0f / 1024.0f) - 0.5f;
        float z[9];
        #pragma unroll
        for (int k = 0; k < 9; ++k)
            z[k] = erf_fast(((float)k - 4.0f - d) * cc);
        unsigned int lo = 0, hi = 0;
        #pragma unroll
        for (int k = 0; k < 4; ++k) {
            const unsigned int qa =
                (unsigned int)(int)rintf(0.5f * (z[k + 1] - z[k]) * QSCALE);
            const unsigned int qb =
                (unsigned int)(int)rintf(0.5f * (z[k + 5] - z[k + 4]) * QSCALE);
            lo |= qa << (8 * k);
            hi |= qb << (8 * k);
        }
        lut[tid] = make_int2((int)lo, (int)hi);
    }
    for (int i = tid; i < NBINS * LDH; i += THREADS) lh[i] = 0;

    const float e0x = edges_x[0];
    const float dxw = edges_x[1] - e0x;
    const float e0y = edges_y[0];
    const float dyw = edges_y[1] - e0y;
    const float ivx = 1.0f / dxw;
    const float ivy = 1.0f / dyw;
    __syncthreads();

    int bsum = 0;
    const int stride = gridDim.x * THREADS;
    for (int p = blockIdx.x * THREADS + tid; p < n; p += stride) {
        // both coordinates in one 8B load (p*24 is 8-aligned)
        const float2 u = *(const float2*)(x + (size_t)p * 6);

        const float sposx = (u.x - e0x) * ivx;
        const float rx = floorf(sposx + 0.5f);
        const int b0x = (int)rx - 4;
        int tix = (int)((sposx - rx + 0.5f) * 1024.0f);
        tix = tix < 0 ? 0 : (tix > 1023 ? 1023 : tix);
        const int2 wxp = lut[tix];

        const float sposy = (u.y - e0y) * ivy;
        const float ry = floorf(sposy + 0.5f);
        const int b0y = (int)ry - 4;
        int tiy = (int)((sposy - ry + 0.5f) * 1024.0f);
        tiy = tiy < 0 ? 0 : (tiy > 1023 ? 1023 : tiy);
        const int2 wyp = lut[tiy];

        int qx[8], qy[8];
        #pragma unroll
        for (int k = 0; k < 4; ++k) {
            qx[k]     = ((unsigned int)wxp.x >> (8 * k)) & 0xFF;
            qx[k + 4] = ((unsigned int)wxp.y >> (8 * k)) & 0xFF;
            qy[k]     = ((unsigned int)wyp.x >> (8 * k)) & 0xFF;
            qy[k + 4] = ((unsigned int)wyp.y >> (8 * k)) & 0xFF;
        }

        // in-range-only sums so btot matches reference hist.sum()
        int sxin = 0, syin = 0;
        #pragma unroll
        for (int k = 0; k < 8; ++k) {
            if ((unsigned)(b0x + k) < (unsigned)NBINS) sxin += qx[k];
            if ((unsigned)(b0y + k) < (unsigned)NBINS) syin += qy[k];
        }
        bsum += sxin * syin;

        #pragma unroll
        for (int i = 0; i < 8; ++i) {
            const int qi = qx[i];
            const int bx = b0x + i;
            if (__any(qi != 0)) {
                const bool vx = (unsigned)bx < (unsigned)NBINS;
                int* const rowp = lh + bx * LDH + b0y;
                #pragma unroll
                for (int j = 0; j < 8; ++j) {
                    const int prod = qi * qy[j];
                    if (vx && (unsigned)(b0y + j) < (unsigned)NBINS && prod)
                        atomicAdd(rowp + j, prod);
                }
            }
        }
    }
    __syncthreads();

    // epilogue: LDS i32 -> bf16 partials. Thread t: 16 consecutive bins
    // (32B contiguous global store as 4x ushort4); c+3 never crosses a row.
    {
        const float qs = 1.0f / (QSCALE * QSCALE);
        unsigned short* my = partials + (size_t)blockIdx.x * NB2;
        #pragma unroll
        for (int v = 0; v < 4; ++v) {
            const int e = tid * 16 + v * 4;
            const int r = e >> 7;
            const int c = e & 127;
            const int* row = lh + r * LDH + c;
            ushort4 o;
            o.x = f2bf((float)row[0] * qs);
            o.y = f2bf((float)row[1] * qs);
            o.z = f2bf((float)row[2] * qs);
            o.w = f2bf((float)row[3] * qs);
            *(ushort4*)(my + e) = o;
        }
    }

    // block total (exact i32 within wave; block sum ~2e8 << 2^31)
    #pragma unroll
    for (int off = 32; off > 0; off >>= 1) bsum += __shfl_down(bsum, off, 64);
    if (lane == 0) xw[wv] = bsum;
    __syncthreads();
    if (tid == 0) {
        const float qs = 1.0f / (QSCALE * QSCALE);
        int s = 0;
        #pragma unroll
        for (int k = 0; k < 16; ++k) s += xw[k];
        btot[blockIdx.x] = (float)s * qs;
    }
}

// Fused reduction + normalize: 256 blocks x 256 threads (measured-good).
// Block B covers bins [B*64, B*64+64). Thread t: bin4 = t&15 (4 bins),
// pgroup = t>>4 (16 partials each, of 256 total).
__global__ void reduce_kernel(const unsigned short* __restrict__ partials,
                              const float* __restrict__ btot,
                              const float* __restrict__ edges_x,
                              const float* __restrict__ edges_y,
                              float* __restrict__ out)
{
    __shared__ float4 red[16][16];
    __shared__ float ws[4];
    __shared__ float stot;

    const int t = threadIdx.x;
    const int bin4 = t & 15;
    const int pg = t >> 4;
    const int binBase = blockIdx.x * 64;

    // grand total (redundant per block; btot is 1KB, L2-hot)
    float tl = btot[t];
    #pragma unroll
    for (int off = 32; off > 0; off >>= 1) tl += __shfl_down(tl, off, 64);
    if ((t & 63) == 0) ws[t >> 6] = tl;

    // sum 16 partials for 4 bins
    const unsigned short* p =
        partials + (size_t)(pg * 16) * NB2 + binBase + bin4 * 4;
    float4 s = {0.f, 0.f, 0.f, 0.f};
    #pragma unroll 8
    for (int k = 0; k < 16; ++k) {
        const ushort4 v = *(const ushort4*)(p + (size_t)k * NB2);
        s.x += bf2f(v.x); s.y += bf2f(v.y); s.z += bf2f(v.z); s.w += bf2f(v.w);
    }
    red[pg][bin4] = s;
    __syncthreads();

    if (t == 0) {
        const float dxw = edges_x[1] - edges_x[0];
        const float dyw = edges_y[1] - edges_y[0];
        stot = 1.0f / ((ws[0] + ws[1] + ws[2] + ws[3]) * dxw * dyw);
    }
    __syncthreads();

    if (t < 16) {
        float4 a = red[0][t];
        #pragma unroll
        for (int g = 1; g < 16; ++g) {
            const float4 b = red[g][t];
            a.x += b.x; a.y += b.y; a.z += b.z; a.w += b.w;
        }
        a.x *= stot; a.y *= stot; a.z *= stot; a.w *= stot;
        *(float4*)(out + binBase + t * 4) = a;
    }
}

extern "C" void kernel_launch(void* const* d_in, const int* in_sizes, int n_in,
                              void* d_out, int out_size, void* d_ws, size_t ws_size,
                              hipStream_t stream)
{
    const float* x  = (const float*)d_in[0];
    const float* ex = (const float*)d_in[1];
    const float* ey = (const float*)d_in[2];
    float* out = (float*)d_out;
    const int n = in_sizes[0] / 6;

    unsigned short* partials = (unsigned short*)d_ws;             // 256*16384 bf16
    float* btot = (float*)((char*)d_ws + (size_t)NBLOCKS * NB2 * 2);  // 256 f32

    hist_sparse_kernel<<<NBLOCKS, THREADS, 0, stream>>>(x, ex, ey, partials, btot, n);
    reduce_kernel<<<NB2 / 64, 256, 0, stream>>>(partials, btot, ex, ey, out);
}

// Round 14
// 75.125 us; speedup vs baseline: 1.0368x; 1.0368x over previous
//
#include <hip/hip_runtime.h>
#include <math.h>

// Histogram2D, sparse formulation: each point adds its exact-i32 window
// outer-product qx[i]*qy[j] into a per-block LDS histogram via LDS atomics
// (CU-local). Ladder: R8 dense-MFMA 84.5 -> R17 sparse 81.9 -> R18 halve
// partials (256 blk x 1024 thr, 8MiB) 76.4 [prediction MATCHED].
// R19 FAILED (77.9, +1.5): LDS weight-LUT + per-lane zero-skip. Lesson:
// hot loop is LDS-ATOMIC-STREAM-bound, not VALU-bound; LUT reads contend
// with atomics on the same pipe and predication adds divergence. Reverted.
// Other FAILED (never revisit): R10 device atomics (+12.7, far coherence
// point), R11 software grid barrier (+150, agent-scope spin), R12 dense
// 100%-occupancy (neutral).
// Decomposition: poison fill ~41.2 (fixed floor, 256MiB d_ws @ 81% peak) +
// harness tiny-dispatch floor ~20 + hist ~7 + reduce ~3.5.
// R20: 8x8 -> 7x7 window, floor-centered — provably q-identical. A bin
// with near edge >= 3 sigma has mass <= 0.00132 -> q = rint(320*m) = 0;
// the floor-centered 7-window [floor(spos)-3, +3] contains every bin that
// can have q >= 1 (needs mass >= 0.5/320, i.e. near edge < ~2.95 sigma).
// The dropped edge bin was always q=0 -> identical output, identical
// absmax. Atomics 64->49 (-23%) on the dominant pipe, erf 18->16, muls
// 64->49, branch-free.
// R21: resubmit unchanged (R20 bench failed: container error, no data).
// Predicted 76.4 -> 74.5-75.8. If neutral: atomic stream smaller than
// modeled; controllable residue ~= reduce only -> assess floor.
// Numerics: A&S erf, q=rint(w*320) (max ~123), exact i32, bf16 partials.
// LDS hist stride 129 i32 -> bank ~(bx+by+c)%32 uniform; 64.5 KiB ->
// 1 block/CU, 16 waves. All 49 atomic offsets compile-time imm.

#define NBINS   128
#define NB2     (NBINS * NBINS)
#define LDH     129               // padded LDS row stride (i32)
#define THREADS 1024
#define NBLOCKS 256
#define QSCALE  320.0f

static __device__ __forceinline__ unsigned short f2bf(float f) {
    unsigned int b = __float_as_uint(f);
    b += 0x7fff + ((b >> 16) & 1);            // RNE
    return (unsigned short)(b >> 16);
}
static __device__ __forceinline__ float bf2f(unsigned short u) {
    return __uint_as_float((unsigned int)u << 16);
}

// Abramowitz-Stegun 7.1.26: |err| <= 1.5e-7, branch-free.
static __device__ __forceinline__ float erf_fast(float x) {
    const float ax = fabsf(x);
    const float t  = __builtin_amdgcn_rcpf(fmaf(0.3275911f, ax, 1.0f));
    const float e  = __expf(-x * x);          // v_exp_f32; inf^2 -> e=0 safe
    float p = fmaf(1.061405429f, t, -1.453152027f);
    p = fmaf(p, t, 1.421413741f);
    p = fmaf(p, t, -0.284496736f);
    p = fmaf(p, t, 0.254829592f);
    p = p * t;
    return copysignf(fmaf(-p, e, 1.0f), x);
}

// Per-axis 7-bin window: base bin b0 (clamped) + 7 quantized weights.
// Window [floor(spos)-3, floor(spos)+3]: captures every bin with q>=1.
static __device__ __forceinline__ void axis_q(
    float u, float e0, float inv, int& b0, int q[7])
{
    const float cc = 0.7071067811865476f;     // 1/sqrt(2); bw = bin width
    const float spos = (u - e0) * inv;
    int b = (int)floorf(spos) - 3;
    b0 = b < 0 ? 0 : (b > NBINS - 7 ? NBINS - 7 : b);
    const float t0 = ((float)b0 - spos) * cc;
    float z[8];
    #pragma unroll
    for (int k = 0; k < 8; ++k) z[k] = erf_fast(t0 + (float)k * cc);
    #pragma unroll
    for (int k = 0; k < 7; ++k)
        q[k] = (int)rintf(0.5f * (z[k + 1] - z[k]) * QSCALE);
}

__global__ __launch_bounds__(THREADS, 4) void hist_sparse_kernel(
    const float* __restrict__ x,
    const float* __restrict__ edges_x,
    const float* __restrict__ edges_y,
    unsigned short* __restrict__ partials,   // bf16 [block][16384]
    float* __restrict__ btot,                // f32 [256]
    int n)
{
    __shared__ int lh[NBINS * LDH];          // 64.5 KiB
    __shared__ int xw[16];

    const int tid  = threadIdx.x;
    const int lane = tid & 63;
    const int wv   = tid >> 6;               // 0..15

    for (int i = tid; i < NBINS * LDH; i += THREADS) lh[i] = 0;

    const float e0x = edges_x[0];
    const float dxw = edges_x[1] - e0x;
    const float e0y = edges_y[0];
    const float dyw = edges_y[1] - e0y;
    const float ivx = 1.0f / dxw;
    const float ivy = 1.0f / dyw;
    __syncthreads();

    int bsum = 0;
    const int stride = gridDim.x * THREADS;
    for (int p = blockIdx.x * THREADS + tid; p < n; p += stride) {
        // both coordinates in one 8B load (p*24 is 8-aligned)
        const float2 u = *(const float2*)(x + (size_t)p * 6);
        int bx0, by0, qx[7], qy[7];
        axis_q(u.x, e0x, ivx, bx0, qx);
        axis_q(u.y, e0y, ivy, by0, qy);

        int sx = 0, sy = 0;
        #pragma unroll
        for (int k = 0; k < 7; ++k) { sx += qx[k]; sy += qy[k]; }
        bsum += sx * sy;                     // exact; all bins in-range post-clamp

        int* const base = lh + bx0 * LDH + by0;
        #pragma unroll
        for (int i = 0; i < 7; ++i) {
            const int qi = qx[i];
            #pragma unroll
            for (int j = 0; j < 7; ++j)
                atomicAdd(base + i * LDH + j, qi * qy[j]);
        }
    }
    __syncthreads();

    // epilogue: LDS i32 -> bf16 partials. Thread t: 16 consecutive bins
    // (32B contiguous global store as 4x ushort4); c+3 never crosses a row.
    {
        const float qs = 1.0f / (QSCALE * QSCALE);
        unsigned short* my = partials + (size_t)blockIdx.x * NB2;
        #pragma unroll
        for (int v = 0; v < 4; ++v) {
            const int e = tid * 16 + v * 4;
            const int r = e >> 7;
            const int c = e & 127;
            const int* row = lh + r * LDH + c;
            ushort4 o;
            o.x = f2bf((float)row[0] * qs);
            o.y = f2bf((float)row[1] * qs);
            o.z = f2bf((float)row[2] * qs);
            o.w = f2bf((float)row[3] * qs);
            *(ushort4*)(my + e) = o;
        }
    }

    // block total (exact i32 within wave; block sum ~2e8 << 2^31)
    #pragma unroll
    for (int off = 32; off > 0; off >>= 1) bsum += __shfl_down(bsum, off, 64);
    if (lane == 0) xw[wv] = bsum;
    __syncthreads();
    if (tid == 0) {
        const float qs = 1.0f / (QSCALE * QSCALE);
        int s = 0;
        #pragma unroll
        for (int k = 0; k < 16; ++k) s += xw[k];
        btot[blockIdx.x] = (float)s * qs;
    }
}

// Fused reduction + normalize: 256 blocks x 256 threads (measured-good).
// Block B covers bins [B*64, B*64+64). Thread t: bin4 = t&15 (4 bins),
// pgroup = t>>4 (16 partials each, of 256 total).
__global__ void reduce_kernel(const unsigned short* __restrict__ partials,
                              const float* __restrict__ btot,
                              const float* __restrict__ edges_x,
                              const float* __restrict__ edges_y,
                              float* __restrict__ out)
{
    __shared__ float4 red[16][16];
    __shared__ float ws[4];
    __shared__ float stot;

    const int t = threadIdx.x;
    const int bin4 = t & 15;
    const int pg = t >> 4;
    const int binBase = blockIdx.x * 64;

    // grand total (redundant per block; btot is 1KB, L2-hot)
    float tl = btot[t];
    #pragma unroll
    for (int off = 32; off > 0; off >>= 1) tl += __shfl_down(tl, off, 64);
    if ((t & 63) == 0) ws[t >> 6] = tl;

    // sum 16 partials for 4 bins
    const unsigned short* p =
        partials + (size_t)(pg * 16) * NB2 + binBase + bin4 * 4;
    float4 s = {0.f, 0.f, 0.f, 0.f};
    #pragma unroll 8
    for (int k = 0; k < 16; ++k) {
        const ushort4 v = *(const ushort4*)(p + (size_t)k * NB2);
        s.x += bf2f(v.x); s.y += bf2f(v.y); s.z += bf2f(v.z); s.w += bf2f(v.w);
    }
    red[pg][bin4] = s;
    __syncthreads();

    if (t == 0) {
        const float dxw = edges_x[1] - edges_x[0];
        const float dyw = edges_y[1] - edges_y[0];
        stot = 1.0f / ((ws[0] + ws[1] + ws[2] + ws[3]) * dxw * dyw);
    }
    __syncthreads();

    if (t < 16) {
        float4 a = red[0][t];
        #pragma unroll
        for (int g = 1; g < 16; ++g) {
            const float4 b = red[g][t];
            a.x += b.x; a.y += b.y; a.z += b.z; a.w += b.w;
        }
        a.x *= stot; a.y *= stot; a.z *= stot; a.w *= stot;
        *(float4*)(out + binBase + t * 4) = a;
    }
}

extern "C" void kernel_launch(void* const* d_in, const int* in_sizes, int n_in,
                              void* d_out, int out_size, void* d_ws, size_t ws_size,
                              hipStream_t stream)
{
    const float* x  = (const float*)d_in[0];
    const float* ex = (const float*)d_in[1];
    const float* ey = (const float*)d_in[2];
    float* out = (float*)d_out;
    const int n = in_sizes[0] / 6;

    unsigned short* partials = (unsigned short*)d_ws;             // 256*16384 bf16
    float* btot = (float*)((char*)d_ws + (size_t)NBLOCKS * NB2 * 2);  // 256 f32

    hist_sparse_kernel<<<NBLOCKS, THREADS, 0, stream>>>(x, ex, ey, partials, btot, n);
    reduce_kernel<<<NB2 / 64, 256, 0, stream>>>(partials, btot, ex, ey, out);
}